// Round 4
// baseline (42.264 us; speedup 1.0000x reference)
//
#include <hip/hip_runtime.h>
#include <hip/hip_bf16.h>

// Problem constants (from the reference)
#define BB   16
#define LL   512
#define MM   2
#define KNB  48
#define HH   128
#define CC   128
#define DIN_ 640
#define H1_  512
#define H2_  256

__device__ __forceinline__ float nz(float x) { return x == x ? x : 0.0f; }

// ---------------------------------------------------------------------------
// Kernel 1: per-batch. Computes, for each of the 2 mutations:
//   - rank of the OTHER mutation's position in this position's sorted
//     neighbor-distance list (== slot in lax.top_k output, stable ties)
//   - the 640-dim embedding [hid1|hid2|mpnn_embed|Ws[mut]|edge_agg]
// then the valid-masked mean over mutations, LayerNorm, ReLU -> x0[b,640].
// ---------------------------------------------------------------------------
__global__ __launch_bounds__(256) void k_embed(
    const float* __restrict__ X,      // [B,L,4,3]
    const int*   __restrict__ mpos,   // [B,2]
    const int*   __restrict__ mwt,    // [B,2]
    const int*   __restrict__ mmut,   // [B,2]
    const float* __restrict__ hid1,   // [B,L,128]
    const float* __restrict__ hid2,   // [B,L,128]
    const float* __restrict__ memb,   // [B,L,128]
    const float* __restrict__ edges,  // [B,L,48,128]
    const float* __restrict__ Wse,    // [21,128]
    const float* __restrict__ ln_g,   // [640]
    const float* __restrict__ ln_b,   // [640]
    float* __restrict__ x0)           // [B,640]  (post-LN, post-ReLU)
{
  const int b = blockIdx.x;
  const int t = threadIdx.x;

  __shared__ float s_agg[DIN_];
  __shared__ float s_red[256];
  __shared__ int   s_rank[2];

  const int p[2]  = { mpos[b * 2 + 0], mpos[b * 2 + 1] };
  const int mu[2] = { mmut[b * 2 + 0], mmut[b * 2 + 1] };
  const int wt[2] = { mwt[b * 2 + 0],  mwt[b * 2 + 1]  };

  float3 ca[2];
  #pragma unroll
  for (int m = 0; m < 2; ++m) {
    const float* a = X + (((size_t)(b * LL + p[m])) * 4 + 1) * 3;
    ca[m] = make_float3(nz(a[0]), nz(a[1]), nz(a[2]));
  }

  // rank of q = p[1-m] among sorted distances from p[m] (fp32, sqrt(d2+eps),
  // stable tie-break by smaller index — matches lax.top_k on -D)
  for (int m = 0; m < 2; ++m) {
    const float3 cp = ca[m];
    const float3 cq = ca[1 - m];
    const int    q  = p[1 - m];
    const float dx = cp.x - cq.x, dy = cp.y - cq.y, dz = cp.z - cq.z;
    const float dq = sqrtf(dx * dx + dy * dy + dz * dz + 1e-6f);
    int cnt = 0;
    for (int j = t; j < LL; j += 256) {
      const float* a = X + (((size_t)(b * LL + j)) * 4 + 1) * 3;
      const float ex = nz(a[0]) - cp.x;
      const float ey = nz(a[1]) - cp.y;
      const float ez = nz(a[2]) - cp.z;
      const float dj = sqrtf(ex * ex + ey * ey + ez * ez + 1e-6f);
      cnt += (dj < dq || (dj == dq && j < q)) ? 1 : 0;
    }
    s_red[t] = (float)cnt;
    __syncthreads();
    for (int s = 128; s > 0; s >>= 1) {
      if (t < s) s_red[t] += s_red[t + s];
      __syncthreads();
    }
    if (t == 0) s_rank[m] = (int)s_red[0];
    __syncthreads();
  }

  const int v0 = ((p[0] + wt[0] + mu[0]) != 0) ? 1 : 0;
  const int v1 = ((p[1] + wt[1] + mu[1]) != 0) ? 1 : 0;
  const float denom = fmaxf((float)(v0 + v1), 1.0f);
  const int rk[2] = { s_rank[0], s_rank[1] };
  const int vv[2] = { v0, v1 };

  // build masked-mean embedding directly
  for (int d = t; d < DIN_; d += 256) {
    float v = 0.0f;
    #pragma unroll
    for (int m = 0; m < 2; ++m) {
      if (!vv[m]) continue;
      const int base = p[m];
      float e;
      if (d < 128)       e = hid1[(size_t)(b * LL + base) * 128 + d];
      else if (d < 256)  e = hid2[(size_t)(b * LL + base) * 128 + (d - 128)];
      else if (d < 384)  e = memb[(size_t)(b * LL + base) * 128 + (d - 256)];
      else if (d < 512)  e = Wse[mu[m] * 128 + (d - 384)];
      else               e = (rk[m] < KNB)
                               ? edges[(((size_t)(b * LL + base)) * KNB + rk[m]) * CC + (d - 512)]
                               : 0.0f;
      v += e;
    }
    s_agg[d] = v / denom;
  }
  __syncthreads();

  // LayerNorm (two-pass) + ReLU
  float ps = 0.0f;
  for (int d = t; d < DIN_; d += 256) ps += s_agg[d];
  s_red[t] = ps;
  __syncthreads();
  for (int s = 128; s > 0; s >>= 1) {
    if (t < s) s_red[t] += s_red[t + s];
    __syncthreads();
  }
  const float mu_ = s_red[0] / (float)DIN_;
  __syncthreads();

  float pv = 0.0f;
  for (int d = t; d < DIN_; d += 256) {
    const float z = s_agg[d] - mu_;
    pv += z * z;
  }
  s_red[t] = pv;
  __syncthreads();
  for (int s = 128; s > 0; s >>= 1) {
    if (t < s) s_red[t] += s_red[t + s];
    __syncthreads();
  }
  const float var = s_red[0] / (float)DIN_;
  const float inv = 1.0f / sqrtf(var + 1e-5f);

  for (int d = t; d < DIN_; d += 256) {
    const float y = (s_agg[d] - mu_) * inv * ln_g[d] + ln_b[d];
    x0[b * DIN_ + d] = fmaxf(y, 0.0f);
  }
}

// ---------------------------------------------------------------------------
// FC layer: xout[b,c] = relu( dot(xin[b,:], W[:,c]) + bias[c] )
// Block owns a 32-column chunk for ALL 16 batch rows -> W fetched once total.
// xin staged entirely in LDS. Thread (bg, c) handles batches bg and bg+8.
// ---------------------------------------------------------------------------
template <int NIN, int NOUT>
__global__ __launch_bounds__(256) void k_fc(
    const float* __restrict__ xin,   // [16, NIN] (already post-ReLU)
    const float* __restrict__ W,     // [NIN, NOUT]
    const float* __restrict__ bias,  // [NOUT]
    float* __restrict__ xout)        // [16, NOUT] (post-ReLU)
{
  __shared__ float xs[16 * NIN];
  const int t = threadIdx.x;
  for (int i = t; i < 16 * NIN; i += 256) xs[i] = xin[i];
  __syncthreads();

  const int c  = blockIdx.x * 32 + (t & 31);
  const int bg = t >> 5;  // 0..7
  const float* xa = xs + bg * NIN;
  const float* xb = xs + (bg + 8) * NIN;

  float acc0 = 0.0f, acc1 = 0.0f;
  for (int r = 0; r < NIN; ++r) {
    const float w = W[(size_t)r * NOUT + c];
    acc0 = fmaf(xa[r], w, acc0);
    acc1 = fmaf(xb[r], w, acc1);
  }
  const float bi = bias[c];
  xout[bg * NOUT + c]       = fmaxf(acc0 + bi, 0.0f);
  xout[(bg + 8) * NOUT + c] = fmaxf(acc1 + bi, 0.0f);
}

// ---------------------------------------------------------------------------
// Final layer: out[b] = dot(x2[b,:], W3[:,0]) + b3
// ---------------------------------------------------------------------------
__global__ __launch_bounds__(256) void k_out(
    const float* __restrict__ x2,  // [16,256] post-ReLU
    const float* __restrict__ W3,  // [256,1]
    const float* __restrict__ b3,  // [1]
    float* __restrict__ out)       // [16]
{
  __shared__ float s_red[256];
  const int b = blockIdx.x, t = threadIdx.x;
  s_red[t] = x2[b * 256 + t] * W3[t];
  __syncthreads();
  for (int s = 128; s > 0; s >>= 1) {
    if (t < s) s_red[t] += s_red[t + s];
    __syncthreads();
  }
  if (t == 0) out[b] = s_red[0] + b3[0];
}

extern "C" void kernel_launch(void* const* d_in, const int* in_sizes, int n_in,
                              void* d_out, int out_size, void* d_ws, size_t ws_size,
                              hipStream_t stream) {
  const float* X     = (const float*)d_in[0];
  const int*   mpos  = (const int*)  d_in[6];
  const int*   mwt   = (const int*)  d_in[7];
  const int*   mmut  = (const int*)  d_in[8];
  const float* hid1  = (const float*)d_in[11];
  const float* hid2  = (const float*)d_in[12];
  const float* memb  = (const float*)d_in[13];
  const float* edges = (const float*)d_in[14];
  const float* Wse   = (const float*)d_in[15];
  const float* ln_g  = (const float*)d_in[16];
  const float* ln_b  = (const float*)d_in[17];
  const float* W1    = (const float*)d_in[18];
  const float* b1    = (const float*)d_in[19];
  const float* W2    = (const float*)d_in[20];
  const float* b2    = (const float*)d_in[21];
  const float* W3    = (const float*)d_in[22];
  const float* b3    = (const float*)d_in[23];

  float* ws = (float*)d_ws;
  float* x0 = ws;                    // 16*640
  float* x1 = x0 + 16 * DIN_;        // 16*512
  float* x2 = x1 + 16 * H1_;         // 16*256
  float* out = (float*)d_out;        // 16

  k_embed<<<BB, 256, 0, stream>>>(X, mpos, mwt, mmut, hid1, hid2, memb,
                                  edges, Wse, ln_g, ln_b, x0);
  k_fc<DIN_, H1_><<<H1_ / 32, 256, 0, stream>>>(x0, W1, b1, x1);
  k_fc<H1_, H2_><<<H2_ / 32, 256, 0, stream>>>(x1, W2, b2, x2);
  k_out<<<BB, 256, 0, stream>>>(x2, W3, b3, out);
}

// Round 5
// 28.353 us; speedup vs baseline: 1.4907x; 1.4907x over previous
//
#include <hip/hip_runtime.h>
#include <hip/hip_bf16.h>

// Problem constants (from the reference)
#define BB   16
#define LL   512
#define KNB  48
#define DIN_ 640
#define H1_  512
#define H2_  256
#define NT   512   // threads per block

__device__ __forceinline__ float nz(float x) { return x == x ? x : 0.0f; }

// ---------------------------------------------------------------------------
// Fully fused: one block per batch element does the ENTIRE pipeline.
//   1) rank of the other mutation's position in this position's sorted
//      neighbor-distance list (stable, == lax.top_k slot); mask is all-ones
//      so D_adj == D and rank-counting is exact.
//   2) 640-dim embedding [hid1|hid2|mpnn_embed|Ws[mut]|edge_agg], valid-masked
//      mean over the 2 mutations.
//   3) LayerNorm + ReLU.
//   4) FC1 640->512 (1 column/thread), ReLU.
//   5) FC2 512->256 fused with the W3 dot (256 threads), block-reduce, +b3.
// W1/W2 are re-read by every block but are L2/L3-resident (1.25 MB + 0.5 MB);
// the batch-sharing that motivated the old 4-kernel split is not worth 3
// extra serial launches (~30 us of the 42 us total).
// ---------------------------------------------------------------------------
__global__ __launch_bounds__(NT) void k_fused(
    const float* __restrict__ X,      // [B,L,4,3]
    const int*   __restrict__ mpos,   // [B,2]
    const int*   __restrict__ mwt,    // [B,2]
    const int*   __restrict__ mmut,   // [B,2]
    const float* __restrict__ hid1,   // [B,L,128]
    const float* __restrict__ hid2,   // [B,L,128]
    const float* __restrict__ memb,   // [B,L,128]
    const float* __restrict__ edges,  // [B,L,48,128]
    const float* __restrict__ Wse,    // [21,128]
    const float* __restrict__ ln_g,   // [640]
    const float* __restrict__ ln_b,   // [640]
    const float* __restrict__ W1,     // [640,512]
    const float* __restrict__ b1,     // [512]
    const float* __restrict__ W2,     // [512,256]
    const float* __restrict__ b2,     // [256]
    const float* __restrict__ W3,     // [256,1]
    const float* __restrict__ b3,     // [1]
    float* __restrict__ out)          // [16]
{
  const int b = blockIdx.x;
  const int t = threadIdx.x;

  __shared__ float s_x0[DIN_];   // agg -> post-LN/ReLU x0 (in-place)
  __shared__ float s_x1[H1_];    // post-ReLU x1
  __shared__ float s_red[NT];
  __shared__ int   s_rank[2];

  const int p[2]  = { mpos[b * 2 + 0], mpos[b * 2 + 1] };
  const int mu[2] = { mmut[b * 2 + 0], mmut[b * 2 + 1] };
  const int wt[2] = { mwt[b * 2 + 0],  mwt[b * 2 + 1]  };

  float3 ca[2];
  #pragma unroll
  for (int m = 0; m < 2; ++m) {
    const float* a = X + (((size_t)(b * LL + p[m])) * 4 + 1) * 3;
    ca[m] = make_float3(nz(a[0]), nz(a[1]), nz(a[2]));
  }

  // ---- phase 1: ranks (one residue per thread; LL == NT) ----
  // my Ca coords for residue t (reused for both m)
  {
    const float* a = X + (((size_t)(b * LL + t)) * 4 + 1) * 3;
    const float jx = nz(a[0]), jy = nz(a[1]), jz = nz(a[2]);
    #pragma unroll
    for (int m = 0; m < 2; ++m) {
      const float3 cp = ca[m];
      const float3 cq = ca[1 - m];
      const int    q  = p[1 - m];
      const float dx = cp.x - cq.x, dy = cp.y - cq.y, dz = cp.z - cq.z;
      const float dq = sqrtf(dx * dx + dy * dy + dz * dz + 1e-6f);
      const float ex = jx - cp.x, ey = jy - cp.y, ez = jz - cp.z;
      const float dj = sqrtf(ex * ex + ey * ey + ez * ez + 1e-6f);
      s_red[t] = (dj < dq || (dj == dq && t < q)) ? 1.0f : 0.0f;
      __syncthreads();
      for (int s = NT / 2; s > 0; s >>= 1) {
        if (t < s) s_red[t] += s_red[t + s];
        __syncthreads();
      }
      if (t == 0) s_rank[m] = (int)s_red[0];
      __syncthreads();
    }
  }

  const int v0 = ((p[0] + wt[0] + mu[0]) != 0) ? 1 : 0;
  const int v1 = ((p[1] + wt[1] + mu[1]) != 0) ? 1 : 0;
  const float denom = fmaxf((float)(v0 + v1), 1.0f);
  const int rk[2] = { s_rank[0], s_rank[1] };
  const int vv[2] = { v0, v1 };

  // ---- phase 2: masked-mean embedding -> s_x0 (pre-LN) ----
  for (int d = t; d < DIN_; d += NT) {
    float v = 0.0f;
    #pragma unroll
    for (int m = 0; m < 2; ++m) {
      if (!vv[m]) continue;
      const int base = p[m];
      float e;
      if (d < 128)       e = hid1[(size_t)(b * LL + base) * 128 + d];
      else if (d < 256)  e = hid2[(size_t)(b * LL + base) * 128 + (d - 128)];
      else if (d < 384)  e = memb[(size_t)(b * LL + base) * 128 + (d - 256)];
      else if (d < 512)  e = Wse[mu[m] * 128 + (d - 384)];
      else               e = (rk[m] < KNB)
                               ? edges[(((size_t)(b * LL + base)) * KNB + rk[m]) * 128 + (d - 512)]
                               : 0.0f;
      v += e;
    }
    s_x0[d] = v / denom;
  }
  __syncthreads();

  // ---- phase 3: LayerNorm (two-pass) + ReLU, in place ----
  float ps = 0.0f;
  for (int d = t; d < DIN_; d += NT) ps += s_x0[d];
  s_red[t] = ps;
  __syncthreads();
  for (int s = NT / 2; s > 0; s >>= 1) {
    if (t < s) s_red[t] += s_red[t + s];
    __syncthreads();
  }
  const float mu_ = s_red[0] / (float)DIN_;
  __syncthreads();

  float pv = 0.0f;
  for (int d = t; d < DIN_; d += NT) {
    const float z = s_x0[d] - mu_;
    pv += z * z;
  }
  s_red[t] = pv;
  __syncthreads();
  for (int s = NT / 2; s > 0; s >>= 1) {
    if (t < s) s_red[t] += s_red[t + s];
    __syncthreads();
  }
  const float var = s_red[0] / (float)DIN_;
  const float inv = 1.0f / sqrtf(var + 1e-5f);
  __syncthreads();  // all reads of s_red done before reuse; s_x0 rewrite is elementwise

  for (int d = t; d < DIN_; d += NT) {
    const float y = (s_x0[d] - mu_) * inv * ln_g[d] + ln_b[d];
    s_x0[d] = fmaxf(y, 0.0f);
  }
  __syncthreads();

  // ---- phase 4: FC1 640->512, one column per thread ----
  {
    float acc = 0.0f;
    for (int r = 0; r < DIN_; ++r)
      acc = fmaf(s_x0[r], W1[(size_t)r * H1_ + t], acc);
    s_x1[t] = fmaxf(acc + b1[t], 0.0f);
  }
  __syncthreads();

  // ---- phase 5: FC2 512->256 fused with W3 dot ----
  float contrib = 0.0f;
  if (t < H2_) {
    float acc = 0.0f;
    for (int r = 0; r < H1_; ++r)
      acc = fmaf(s_x1[r], W2[(size_t)r * H2_ + t], acc);
    contrib = fmaxf(acc + b2[t], 0.0f) * W3[t];
  }
  s_red[t] = contrib;
  __syncthreads();
  for (int s = NT / 2; s > 0; s >>= 1) {
    if (t < s) s_red[t] += s_red[t + s];
    __syncthreads();
  }
  if (t == 0) out[b] = s_red[0] + b3[0];
}

extern "C" void kernel_launch(void* const* d_in, const int* in_sizes, int n_in,
                              void* d_out, int out_size, void* d_ws, size_t ws_size,
                              hipStream_t stream) {
  const float* X     = (const float*)d_in[0];
  const int*   mpos  = (const int*)  d_in[6];
  const int*   mwt   = (const int*)  d_in[7];
  const int*   mmut  = (const int*)  d_in[8];
  const float* hid1  = (const float*)d_in[11];
  const float* hid2  = (const float*)d_in[12];
  const float* memb  = (const float*)d_in[13];
  const float* edges = (const float*)d_in[14];
  const float* Wse   = (const float*)d_in[15];
  const float* ln_g  = (const float*)d_in[16];
  const float* ln_b  = (const float*)d_in[17];
  const float* W1    = (const float*)d_in[18];
  const float* b1    = (const float*)d_in[19];
  const float* W2    = (const float*)d_in[20];
  const float* b2    = (const float*)d_in[21];
  const float* W3    = (const float*)d_in[22];
  const float* b3    = (const float*)d_in[23];

  float* out = (float*)d_out;  // [16]

  k_fused<<<BB, NT, 0, stream>>>(X, mpos, mwt, mmut, hid1, hid2, memb, edges,
                                 Wse, ln_g, ln_b, W1, b1, W2, b2, W3, b3, out);
}

// Round 6
// 22.429 us; speedup vs baseline: 1.8844x; 1.2641x over previous
//
#include <hip/hip_runtime.h>
#include <hip/hip_bf16.h>

// Problem constants (from the reference)
#define BB   16
#define LL   512
#define KNB  48
#define DIN_ 640
#define H1_  512
#define H2_  256
#define NT   512   // threads per block == LL

__device__ __forceinline__ float nz(float x) { return x == x ? x : 0.0f; }

// 64-lane butterfly sum (no barrier needed within a wave)
__device__ __forceinline__ float wave_sum(float v) {
  #pragma unroll
  for (int m = 32; m >= 1; m >>= 1) v += __shfl_xor(v, m);
  return v;
}

// ---------------------------------------------------------------------------
// One block per batch element, fully fused, barrier-minimized:
//   1) rank of other mutation in sorted neighbor list: per-thread predicate
//      -> __ballot + popcount (1 barrier).  Stable-tie semantics == lax.top_k.
//   2) 640-dim masked-mean embedding.
//   3) LayerNorm via shuffle reductions (2 barriers) + ReLU.
//   4) FC1 640->512, one column/thread, 8 accumulators for ILP.
//   5) FC2 512->256 split over all 512 threads (two half-dots) + W3 dot,
//      shuffle-reduced.  ~8 barriers total vs ~40 before.
// ---------------------------------------------------------------------------
__global__ __launch_bounds__(NT) void k_fused(
    const float* __restrict__ X,      // [B,L,4,3]
    const int*   __restrict__ mpos,   // [B,2]
    const int*   __restrict__ mwt,    // [B,2]
    const int*   __restrict__ mmut,   // [B,2]
    const float* __restrict__ hid1,   // [B,L,128]
    const float* __restrict__ hid2,   // [B,L,128]
    const float* __restrict__ memb,   // [B,L,128]
    const float* __restrict__ edges,  // [B,L,48,128]
    const float* __restrict__ Wse,    // [21,128]
    const float* __restrict__ ln_g,   // [640]
    const float* __restrict__ ln_b,   // [640]
    const float* __restrict__ W1,     // [640,512]
    const float* __restrict__ b1,     // [512]
    const float* __restrict__ W2,     // [512,256]
    const float* __restrict__ b2,     // [256]
    const float* __restrict__ W3,     // [256,1]
    const float* __restrict__ b3,     // [1]
    float* __restrict__ out)          // [16]
{
  const int b   = blockIdx.x;
  const int t   = threadIdx.x;
  const int wid = t >> 6;            // wave id 0..7

  __shared__ float s_x0[DIN_];       // embedding -> post-LN/ReLU (in place)
  __shared__ float s_x1[H1_];        // post-ReLU FC1 output
  __shared__ float s_p2[NT];         // FC2 half-dot partials
  __shared__ float s_w[24];          // [0..7] sum, [8..15] var, [16..23] final
  __shared__ int   s_cnt[16];        // rank popcounts: [0..7] m=0, [8..15] m=1

  const int p[2]  = { mpos[b * 2 + 0], mpos[b * 2 + 1] };
  const int mu[2] = { mmut[b * 2 + 0], mmut[b * 2 + 1] };
  const int wt[2] = { mwt[b * 2 + 0],  mwt[b * 2 + 1]  };

  float3 ca[2];
  #pragma unroll
  for (int m = 0; m < 2; ++m) {
    const float* a = X + (((size_t)(b * LL + p[m])) * 4 + 1) * 3;
    ca[m] = make_float3(nz(a[0]), nz(a[1]), nz(a[2]));
  }

  // ---- phase 1: ranks via ballot/popcount (1 barrier) ----
  {
    const float* a = X + (((size_t)(b * LL + t)) * 4 + 1) * 3;
    const float jx = nz(a[0]), jy = nz(a[1]), jz = nz(a[2]);
    // dq is symmetric in m (squared diffs identical bit-for-bit)
    const float dx = ca[0].x - ca[1].x, dy = ca[0].y - ca[1].y, dz = ca[0].z - ca[1].z;
    const float dq = sqrtf(dx * dx + dy * dy + dz * dz + 1e-6f);

    const float e0x = jx - ca[0].x, e0y = jy - ca[0].y, e0z = jz - ca[0].z;
    const float d0  = sqrtf(e0x * e0x + e0y * e0y + e0z * e0z + 1e-6f);
    const float e1x = jx - ca[1].x, e1y = jy - ca[1].y, e1z = jz - ca[1].z;
    const float d1  = sqrtf(e1x * e1x + e1y * e1y + e1z * e1z + 1e-6f);

    const bool pr0 = (d0 < dq) || (d0 == dq && t < p[1]);  // rank of p[1] from p[0]
    const bool pr1 = (d1 < dq) || (d1 == dq && t < p[0]);  // rank of p[0] from p[1]
    const unsigned long long m0 = __ballot(pr0);
    const unsigned long long m1 = __ballot(pr1);
    if ((t & 63) == 0) {
      s_cnt[wid]     = __popcll(m0);
      s_cnt[8 + wid] = __popcll(m1);
    }
  }
  __syncthreads();

  int rk[2] = { 0, 0 };
  #pragma unroll
  for (int w = 0; w < 8; ++w) { rk[0] += s_cnt[w]; rk[1] += s_cnt[8 + w]; }

  const int v0 = ((p[0] + wt[0] + mu[0]) != 0) ? 1 : 0;
  const int v1 = ((p[1] + wt[1] + mu[1]) != 0) ? 1 : 0;
  const float denom = fmaxf((float)(v0 + v1), 1.0f);
  const int vv[2] = { v0, v1 };

  // ---- phase 2: masked-mean embedding -> s_x0 ----
  {
    const int d = t;  // threads 0..511 cover d<512; d in [512,640) handled below
    if (true) {
      float v = 0.0f;
      #pragma unroll
      for (int m = 0; m < 2; ++m) {
        if (!vv[m]) continue;
        const int base = p[m];
        float e;
        if (d < 128)      e = hid1[(size_t)(b * LL + base) * 128 + d];
        else if (d < 256) e = hid2[(size_t)(b * LL + base) * 128 + (d - 128)];
        else if (d < 384) e = memb[(size_t)(b * LL + base) * 128 + (d - 256)];
        else              e = Wse[mu[m] * 128 + (d - 384)];
        v += e;
      }
      s_x0[d] = v / denom;
    }
    if (t < DIN_ - NT) {  // d = 512 + t for t<128 : edge_agg slice
      const int d = NT + t;
      float v = 0.0f;
      #pragma unroll
      for (int m = 0; m < 2; ++m) {
        if (!vv[m]) continue;
        if (rk[m] < KNB)
          v += edges[(((size_t)(b * LL + p[m])) * KNB + rk[m]) * 128 + (d - 512)];
      }
      s_x0[d] = v / denom;
    }
  }
  __syncthreads();

  // ---- phase 3: LayerNorm (shuffle reductions) + ReLU in place ----
  float ps = s_x0[t] + ((t < DIN_ - NT) ? s_x0[NT + t] : 0.0f);
  ps = wave_sum(ps);
  if ((t & 63) == 0) s_w[wid] = ps;
  __syncthreads();
  float mu_ = 0.0f;
  #pragma unroll
  for (int w = 0; w < 8; ++w) mu_ += s_w[w];
  mu_ /= (float)DIN_;

  float z0 = s_x0[t] - mu_;
  float pv = z0 * z0;
  if (t < DIN_ - NT) { const float z1 = s_x0[NT + t] - mu_; pv += z1 * z1; }
  pv = wave_sum(pv);
  if ((t & 63) == 0) s_w[8 + wid] = pv;
  __syncthreads();
  float var = 0.0f;
  #pragma unroll
  for (int w = 0; w < 8; ++w) var += s_w[8 + w];
  var /= (float)DIN_;
  const float inv = 1.0f / sqrtf(var + 1e-5f);

  // rewrite s_x0 (elementwise, same slots each thread wrote partials from)
  s_x0[t] = fmaxf((s_x0[t] - mu_) * inv * ln_g[t] + ln_b[t], 0.0f);
  if (t < DIN_ - NT)
    s_x0[NT + t] = fmaxf((s_x0[NT + t] - mu_) * inv * ln_g[NT + t] + ln_b[NT + t], 0.0f);
  __syncthreads();

  // ---- phase 4: FC1 640->512, one column per thread, 8 accumulators ----
  {
    const float* wp = W1 + t;  // column t, row stride H1_
    float a0 = 0.f, a1 = 0.f, a2 = 0.f, a3 = 0.f,
          a4 = 0.f, a5 = 0.f, a6 = 0.f, a7 = 0.f;
    for (int r = 0; r < DIN_; r += 8) {
      a0 = fmaf(s_x0[r + 0], wp[(size_t)(r + 0) * H1_], a0);
      a1 = fmaf(s_x0[r + 1], wp[(size_t)(r + 1) * H1_], a1);
      a2 = fmaf(s_x0[r + 2], wp[(size_t)(r + 2) * H1_], a2);
      a3 = fmaf(s_x0[r + 3], wp[(size_t)(r + 3) * H1_], a3);
      a4 = fmaf(s_x0[r + 4], wp[(size_t)(r + 4) * H1_], a4);
      a5 = fmaf(s_x0[r + 5], wp[(size_t)(r + 5) * H1_], a5);
      a6 = fmaf(s_x0[r + 6], wp[(size_t)(r + 6) * H1_], a6);
      a7 = fmaf(s_x0[r + 7], wp[(size_t)(r + 7) * H1_], a7);
    }
    const float acc = ((a0 + a1) + (a2 + a3)) + ((a4 + a5) + (a6 + a7));
    s_x1[t] = fmaxf(acc + b1[t], 0.0f);
  }
  __syncthreads();

  // ---- phase 5: FC2 512->256 over all 512 threads + W3 dot ----
  {
    const int c = t & (H2_ - 1);        // column 0..255
    const int h = t >> 8;               // half 0/1
    const float* wp = W2 + (size_t)(h * 256) * H2_ + c;
    const float* xp = s_x1 + h * 256;
    float a0 = 0.f, a1 = 0.f, a2 = 0.f, a3 = 0.f;
    for (int r = 0; r < 256; r += 4) {
      a0 = fmaf(xp[r + 0], wp[(size_t)(r + 0) * H2_], a0);
      a1 = fmaf(xp[r + 1], wp[(size_t)(r + 1) * H2_], a1);
      a2 = fmaf(xp[r + 2], wp[(size_t)(r + 2) * H2_], a2);
      a3 = fmaf(xp[r + 3], wp[(size_t)(r + 3) * H2_], a3);
    }
    s_p2[t] = (a0 + a1) + (a2 + a3);
  }
  __syncthreads();

  // combine halves, ReLU, multiply by W3, block-reduce
  float contrib = 0.0f;
  if (t < H2_)
    contrib = fmaxf(s_p2[t] + s_p2[t + 256] + b2[t], 0.0f) * W3[t];
  contrib = wave_sum(contrib);
  if ((t & 63) == 0) s_w[16 + wid] = contrib;
  __syncthreads();
  if (t == 0) {
    float s = 0.0f;
    #pragma unroll
    for (int w = 0; w < 8; ++w) s += s_w[16 + w];
    out[b] = s + b3[0];
  }
}

extern "C" void kernel_launch(void* const* d_in, const int* in_sizes, int n_in,
                              void* d_out, int out_size, void* d_ws, size_t ws_size,
                              hipStream_t stream) {
  const float* X     = (const float*)d_in[0];
  const int*   mpos  = (const int*)  d_in[6];
  const int*   mwt   = (const int*)  d_in[7];
  const int*   mmut  = (const int*)  d_in[8];
  const float* hid1  = (const float*)d_in[11];
  const float* hid2  = (const float*)d_in[12];
  const float* memb  = (const float*)d_in[13];
  const float* edges = (const float*)d_in[14];
  const float* Wse   = (const float*)d_in[15];
  const float* ln_g  = (const float*)d_in[16];
  const float* ln_b  = (const float*)d_in[17];
  const float* W1    = (const float*)d_in[18];
  const float* b1    = (const float*)d_in[19];
  const float* W2    = (const float*)d_in[20];
  const float* b2    = (const float*)d_in[21];
  const float* W3    = (const float*)d_in[22];
  const float* b3    = (const float*)d_in[23];

  float* out = (float*)d_out;  // [16]

  k_fused<<<BB, NT, 0, stream>>>(X, mpos, mwt, mmut, hid1, hid2, memb, edges,
                                 Wse, ln_g, ln_b, W1, b1, W2, b2, W3, b3, out);
}

// Round 8
// 22.054 us; speedup vs baseline: 1.9164x; 1.0170x over previous
//
#include <hip/hip_runtime.h>
#include <hip/hip_bf16.h>

// Problem constants (from the reference)
#define BB   16
#define LL   512
#define KNB  48
#define DIN_ 640
#define H1_  512
#define H2_  256
#define NT   1024  // 16 waves/block, 4 waves/SIMD

__device__ __forceinline__ float nz(float x) { return x == x ? x : 0.0f; }

__device__ __forceinline__ float wave_sum(float v) {
  #pragma unroll
  for (int m = 32; m >= 1; m >>= 1) v += __shfl_xor(v, m);
  return v;
}

// ---------------------------------------------------------------------------
// One block per batch element, fully fused.
//   1) rank via ballot/popcount (exact lax.top_k stable-tie semantics).
//   2) 640-dim masked-mean embedding (one element/thread).
//   3) LayerNorm via shuffle reductions + ReLU.
//   4) FC1 640->512: float4 column-groups x 8 row-slices; wave loads are
//      1KB contiguous, s_x0 reads are wave-uniform broadcasts. LDS combine.
//   5) FC2 512->256: float4 column-groups x 16 row-slices + W3 dot.
// ---------------------------------------------------------------------------
__global__ __launch_bounds__(NT) void k_fused(
    const float* __restrict__ X,      // [B,L,4,3]
    const int*   __restrict__ mpos,   // [B,2]
    const int*   __restrict__ mwt,    // [B,2]
    const int*   __restrict__ mmut,   // [B,2]
    const float* __restrict__ hid1,   // [B,L,128]
    const float* __restrict__ hid2,   // [B,L,128]
    const float* __restrict__ memb,   // [B,L,128]
    const float* __restrict__ edges,  // [B,L,48,128]
    const float* __restrict__ Wse,    // [21,128]
    const float* __restrict__ ln_g,   // [640]
    const float* __restrict__ ln_b,   // [640]
    const float* __restrict__ W1,     // [640,512]
    const float* __restrict__ b1,     // [512]
    const float* __restrict__ W2,     // [512,256]
    const float* __restrict__ b2,     // [256]
    const float* __restrict__ W3,     // [256,1]
    const float* __restrict__ b3,     // [1]
    float* __restrict__ out)          // [16]
{
  const int b   = blockIdx.x;
  const int t   = threadIdx.x;
  const int wid = t >> 6;            // wave id 0..15

  __shared__ float s_x0[DIN_];       // embedding -> post-LN/ReLU (in place)
  __shared__ float s_x1[H1_];        // post-ReLU FC1 output
  __shared__ float s_fc[4096];       // FC partials: FC1 [8][128][4] / FC2 [16][64][4]
  __shared__ float s_w[48];          // [0..15] LN sum, [16..31] LN var, [32..47] final
  __shared__ int   s_cnt[32];        // rank popcounts per wave: [0..15] m0, [16..31] m1

  const int p[2]  = { mpos[b * 2 + 0], mpos[b * 2 + 1] };
  const int mu[2] = { mmut[b * 2 + 0], mmut[b * 2 + 1] };
  const int wt[2] = { mwt[b * 2 + 0],  mwt[b * 2 + 1]  };

  float3 ca[2];
  #pragma unroll
  for (int m = 0; m < 2; ++m) {
    const float* a = X + (((size_t)(b * LL + p[m])) * 4 + 1) * 3;
    ca[m] = make_float3(nz(a[0]), nz(a[1]), nz(a[2]));
  }

  // ---- phase 1: ranks via ballot/popcount ----
  {
    bool pr0 = false, pr1 = false;
    if (t < LL) {
      const float* a = X + (((size_t)(b * LL + t)) * 4 + 1) * 3;
      const float jx = nz(a[0]), jy = nz(a[1]), jz = nz(a[2]);
      // inter-mutation distance (symmetric, identical fp32 both directions)
      const float dx = ca[0].x - ca[1].x, dy = ca[0].y - ca[1].y, dz = ca[0].z - ca[1].z;
      const float dq = sqrtf(dx * dx + dy * dy + dz * dz + 1e-6f);

      const float e0x = jx - ca[0].x, e0y = jy - ca[0].y, e0z = jz - ca[0].z;
      const float d0  = sqrtf(e0x * e0x + e0y * e0y + e0z * e0z + 1e-6f);
      const float e1x = jx - ca[1].x, e1y = jy - ca[1].y, e1z = jz - ca[1].z;
      const float d1  = sqrtf(e1x * e1x + e1y * e1y + e1z * e1z + 1e-6f);

      pr0 = (d0 < dq) || (d0 == dq && t < p[1]);  // rank of p[1] from p[0]
      pr1 = (d1 < dq) || (d1 == dq && t < p[0]);  // rank of p[0] from p[1]
    }
    const unsigned long long m0 = __ballot(pr0);
    const unsigned long long m1 = __ballot(pr1);
    if ((t & 63) == 0) {
      s_cnt[wid]      = __popcll(m0);
      s_cnt[16 + wid] = __popcll(m1);
    }
  }
  __syncthreads();

  int rk[2] = { 0, 0 };
  #pragma unroll
  for (int w = 0; w < 16; ++w) { rk[0] += s_cnt[w]; rk[1] += s_cnt[16 + w]; }

  const int v0 = ((p[0] + wt[0] + mu[0]) != 0) ? 1 : 0;
  const int v1 = ((p[1] + wt[1] + mu[1]) != 0) ? 1 : 0;
  const float denom = fmaxf((float)(v0 + v1), 1.0f);
  const int vv[2] = { v0, v1 };

  // ---- phase 2: masked-mean embedding -> s_x0 (one element/thread) ----
  if (t < DIN_) {
    const int d = t;
    float v = 0.0f;
    #pragma unroll
    for (int m = 0; m < 2; ++m) {
      if (!vv[m]) continue;
      const int base = p[m];
      float e;
      if (d < 128)      e = hid1[(size_t)(b * LL + base) * 128 + d];
      else if (d < 256) e = hid2[(size_t)(b * LL + base) * 128 + (d - 128)];
      else if (d < 384) e = memb[(size_t)(b * LL + base) * 128 + (d - 256)];
      else if (d < 512) e = Wse[mu[m] * 128 + (d - 384)];
      else              e = (rk[m] < KNB)
                              ? edges[(((size_t)(b * LL + base)) * KNB + rk[m]) * 128 + (d - 512)]
                              : 0.0f;
      v += e;
    }
    s_x0[d] = v / denom;
  }
  __syncthreads();

  // ---- phase 3: LayerNorm (shuffle reductions) + ReLU in place ----
  float ps = (t < DIN_) ? s_x0[t] : 0.0f;
  ps = wave_sum(ps);
  if ((t & 63) == 0) s_w[wid] = ps;
  __syncthreads();
  float mu_ = 0.0f;
  #pragma unroll
  for (int w = 0; w < 16; ++w) mu_ += s_w[w];
  mu_ /= (float)DIN_;

  float pv = 0.0f;
  if (t < DIN_) { const float z = s_x0[t] - mu_; pv = z * z; }
  pv = wave_sum(pv);
  if ((t & 63) == 0) s_w[16 + wid] = pv;
  __syncthreads();
  float var = 0.0f;
  #pragma unroll
  for (int w = 0; w < 16; ++w) var += s_w[16 + w];
  var /= (float)DIN_;
  const float inv = 1.0f / sqrtf(var + 1e-5f);

  if (t < DIN_)
    s_x0[t] = fmaxf((s_x0[t] - mu_) * inv * ln_g[t] + ln_b[t], 0.0f);
  __syncthreads();

  // ---- phase 4: FC1 640->512 (float4 column-groups x 8 row-slices) ----
  {
    const int g  = t & 127;     // column-group (4 cols each)
    const int sl = t >> 7;      // row-slice 0..7 (80 rows each)
    const int r0 = sl * 80;
    float4 a = make_float4(0.f, 0.f, 0.f, 0.f);
    #pragma unroll 8
    for (int i = 0; i < 80; ++i) {
      const int r = r0 + i;
      const float xv = s_x0[r];                       // wave-uniform broadcast
      const float4 w = reinterpret_cast<const float4*>(W1 + (size_t)r * H1_)[g];
      a.x = fmaf(xv, w.x, a.x);
      a.y = fmaf(xv, w.y, a.y);
      a.z = fmaf(xv, w.z, a.z);
      a.w = fmaf(xv, w.w, a.w);
    }
    reinterpret_cast<float4*>(s_fc)[sl * 128 + g] = a;
  }
  __syncthreads();
  if (t < H1_) {
    float acc = 0.0f;
    #pragma unroll
    for (int sl = 0; sl < 8; ++sl) acc += s_fc[sl * 512 + t];
    s_x1[t] = fmaxf(acc + b1[t], 0.0f);
  }
  __syncthreads();

  // ---- phase 5: FC2 512->256 (float4 column-groups x 16 row-slices) ----
  {
    const int g  = t & 63;      // column-group (4 cols each)
    const int sl = t >> 6;      // row-slice 0..15 (32 rows each) == wid
    const int r0 = sl * 32;
    float4 a = make_float4(0.f, 0.f, 0.f, 0.f);
    #pragma unroll 8
    for (int i = 0; i < 32; ++i) {
      const int r = r0 + i;
      const float xv = s_x1[r];                       // wave-uniform broadcast
      const float4 w = reinterpret_cast<const float4*>(W2 + (size_t)r * H2_)[g];
      a.x = fmaf(xv, w.x, a.x);
      a.y = fmaf(xv, w.y, a.y);
      a.z = fmaf(xv, w.z, a.z);
      a.w = fmaf(xv, w.w, a.w);
    }
    reinterpret_cast<float4*>(s_fc)[sl * 64 + g] = a;
  }
  __syncthreads();

  float contrib = 0.0f;
  if (t < H2_) {
    float acc = 0.0f;
    #pragma unroll
    for (int sl = 0; sl < 16; ++sl) acc += s_fc[sl * 256 + t];
    contrib = fmaxf(acc + b2[t], 0.0f) * W3[t];
  }
  contrib = wave_sum(contrib);
  if ((t & 63) == 0) s_w[32 + wid] = contrib;
  __syncthreads();
  if (t == 0) {
    float s = 0.0f;
    #pragma unroll
    for (int w = 0; w < 16; ++w) s += s_w[32 + w];
    out[b] = s + b3[0];
  }
}

extern "C" void kernel_launch(void* const* d_in, const int* in_sizes, int n_in,
                              void* d_out, int out_size, void* d_ws, size_t ws_size,
                              hipStream_t stream) {
  const float* X     = (const float*)d_in[0];
  const int*   mpos  = (const int*)  d_in[6];
  const int*   mwt   = (const int*)  d_in[7];
  const int*   mmut  = (const int*)  d_in[8];
  const float* hid1  = (const float*)d_in[11];
  const float* hid2  = (const float*)d_in[12];
  const float* memb  = (const float*)d_in[13];
  const float* edges = (const float*)d_in[14];
  const float* Wse   = (const float*)d_in[15];
  const float* ln_g  = (const float*)d_in[16];
  const float* ln_b  = (const float*)d_in[17];
  const float* W1    = (const float*)d_in[18];
  const float* b1    = (const float*)d_in[19];
  const float* W2    = (const float*)d_in[20];
  const float* b2    = (const float*)d_in[21];
  const float* W3    = (const float*)d_in[22];
  const float* b3    = (const float*)d_in[23];

  float* out = (float*)d_out;  // [16]

  k_fused<<<BB, NT, 0, stream>>>(X, mpos, mwt, mmut, hid1, hid2, memb, edges,
                                 Wse, ln_g, ln_b, W1, b1, W2, b2, W3, b3, out);
}